// Round 6
// baseline (283.324 us; speedup 1.0000x reference)
//
#include <hip/hip_runtime.h>

#define MODE_QKV 0
#define MODE_S   1
#define MODE_PV  2

typedef __attribute__((ext_vector_type(8))) short short8;
typedef __attribute__((ext_vector_type(4))) float floatx4;

typedef const unsigned __attribute__((address_space(1)))* gp_t;
typedef unsigned __attribute__((address_space(3)))* lp_t;

__device__ __forceinline__ void async16(const void* g, void* l) {
  // stages 16B/lane: LDS dest = wave-uniform base + lane*16
  __builtin_amdgcn_global_load_lds((gp_t)g, (lp_t)l, 16, 0, 0);
}

__device__ __forceinline__ unsigned short f2bf(float f) {
  union { float f; unsigned u; } x; x.f = f;
  unsigned r = x.u + 0x7fffu + ((x.u >> 16) & 1u);
  return (unsigned short)(r >> 16);
}
__device__ __forceinline__ float bf2f(unsigned short h) {
  union { unsigned u; float f; } x; x.u = ((unsigned)h) << 16;
  return x.f;
}

// LDS budget pinned to 32768 B (<=2x16KiB granules -> up to 5 blocks/CU):
//  - staging: two BK=32 panels (proven conflict-free layout), 32 KB
//  - epilogue HALF-tiles alias the staging space:
//      epiN[64][136]  (normal, 17408 B)   epiT[128][72] (vtrans, 18432 B)
union SmemU {
  struct { unsigned short A[2][4096]; unsigned short B[2][4096]; } st;  // 32768
  unsigned short epiN[64 * 136];
  unsigned short epiT[128 * 72];
};

// ---------------------------------------------------------------------------
// Unified NT bf16 GEMM: A [M][K] k-contig, B [N][K] k-contig, 128x128 tile,
// BK=64 (2 panels), 256 thr = 4 waves, 4x4 of mfma_f32_16x16x32_bf16 / wave.
//   MODE_QKV: z picks B slice + bias + out; z==2 writes v TRANSPOSED [B][D][S]
//   MODE_S:   out bf16 = exp(acc*scale) (scores bounded, no max-subtract
//             needed), row exp-sums atomicAdd'ed into lsum (pre-zeroed)
//   MODE_PV:  out fp32 = acc / lsum[row]
// Grid swizzled in-kernel: XCD-aware 4x4 block squares. Requires
// gridDim.x%4==0, gridDim.y%4==0, total blocks %128==0.
// Epilogue runs in two 64-row halves so LDS stays at 32768 B; with a 16 KiB
// LDS granule that allows up to 5 blocks/CU (R5: 34816B capped us at 3).
// ---------------------------------------------------------------------------
template<int MODE>
__global__ __launch_bounds__(256, 5)
void gemm_nt(const unsigned short* __restrict__ A,
             const unsigned short* __restrict__ Bmat,
             const float* __restrict__ b0, const float* __restrict__ b1,
             const float* __restrict__ b2,
             unsigned short* __restrict__ O0, unsigned short* __restrict__ O1,
             unsigned short* __restrict__ O2,
             float* __restrict__ Of, float* __restrict__ lsum,
             int M, int N, int K, long aZ, long bZ, long cZ, float scale)
{
  __shared__ SmemU smem;

  const int tid = threadIdx.x;
  const int wave = tid >> 6, lane = tid & 63;
  const int wm = wave >> 1, wn = wave & 1;
  const int quad = lane >> 4, l16 = lane & 15;

  // ---- XCD-aware 4x4-square swizzle ----
  const int gx = gridDim.x, gy = gridDim.y;
  int z, bm, bn;
  {
    int f = (blockIdx.z * gy + blockIdx.y) * gx + blockIdx.x;
    int T = gx * gy * (int)gridDim.z;
    int nsq = T >> 7;                 // 4x4-squares per XCD
    int xcd = f & 7, i = f >> 3;
    int sq = xcd * nsq + (i >> 4);
    int w = i & 15;
    int spz = (gx >> 2) * (gy >> 2);  // squares per z-slice
    z = sq / spz;
    int sqr = sq - z * spz;
    int sqm = sqr / (gx >> 2), sqn = sqr - sqm * (gx >> 2);
    bm = (sqm * 4 + (w >> 2)) * 128;
    bn = (sqn * 4 + (w & 3)) * 128;
  }

  const unsigned short* Ap = (MODE == MODE_QKV) ? A : (A + (long)z * aZ);
  const unsigned short* Bp = Bmat + (long)z * bZ;

  floatx4 acc[4][4];
  #pragma unroll
  for (int i = 0; i < 4; i++)
    #pragma unroll
    for (int j = 0; j < 4; j++)
      acc[i][j] = (floatx4){0.f, 0.f, 0.f, 0.f};

  char* asb = (char*)&smem.st.A[0][0] + wave * 1024;
  char* bsb = (char*)&smem.st.B[0][0] + wave * 1024;

  for (int k0 = 0; k0 < K; k0 += 64) {
    #pragma unroll
    for (int p = 0; p < 2; p++) {
      #pragma unroll
      for (int h = 0; h < 2; h++) {
        int flat = tid + h * 256;        // 16B-chunk index within panel
        int r = flat >> 2, c = (flat & 3) << 3;
        async16(Ap + (long)(bm + r) * K + k0 + p * 32 + c,
                asb + p * 8192 + h * 4096);
        async16(Bp + (long)(bn + r) * K + k0 + p * 32 + c,
                bsb + p * 8192 + h * 4096);
      }
    }
    __syncthreads();

    #pragma unroll
    for (int ks = 0; ks < 2; ks++) {
      short8 afr[4], bfr[4];
      #pragma unroll
      for (int i = 0; i < 4; i++)
        afr[i] = *(const short8*)&smem.st.A[ks][(wm * 64 + i * 16 + l16) * 32 + quad * 8];
      #pragma unroll
      for (int i = 0; i < 4; i++)
        bfr[i] = *(const short8*)&smem.st.B[ks][(wn * 64 + i * 16 + l16) * 32 + quad * 8];
      #pragma unroll
      for (int mi = 0; mi < 4; mi++)
        #pragma unroll
        for (int ni = 0; ni < 4; ni++)
          acc[mi][ni] = __builtin_amdgcn_mfma_f32_16x16x32_bf16(
              afr[mi], bfr[ni], acc[mi][ni], 0, 0, 0);
    }
    __syncthreads();
  }
  // (loop-trailing __syncthreads: staging reads complete; epi may alias st)

  // ---- epilogue; C/D layout: col=lane&15, row=quad*4+reg ----
  if (MODE == MODE_PV) {
    // fp32 direct stores, normalized by the row's exp-sum
    #pragma unroll
    for (int mi = 0; mi < 4; mi++) {
      int row0 = bm + wm * 64 + mi * 16 + quad * 4;
      float inv[4];
      #pragma unroll
      for (int r = 0; r < 4; r++)
        inv[r] = 1.0f / lsum[(long)z * M + row0 + r];
      #pragma unroll
      for (int ni = 0; ni < 4; ni++) {
        int col = bn + wn * 64 + ni * 16 + l16;
        #pragma unroll
        for (int r = 0; r < 4; r++)
          Of[(long)z * cZ + (long)(row0 + r) * N + col] = acc[mi][ni][r] * inv[r];
      }
    }
    return;
  }

  const bool vtrans = (MODE == MODE_QKV) && (z == 2);
  float bi[4];
  if (MODE == MODE_QKV) {
    const float* bias = (z == 0) ? b0 : ((z == 1) ? b1 : b2);
    #pragma unroll
    for (int ni = 0; ni < 4; ni++) bi[ni] = bias[bn + wn * 64 + ni * 16 + l16];
  }

  // Two 64-row halves; the two waves with wm==half own the rows of that half.
  #pragma unroll
  for (int half = 0; half < 2; half++) {
    if (wm == half) {
      #pragma unroll
      for (int ni = 0; ni < 4; ni++) {
        int col = wn * 64 + ni * 16 + l16;
        float bb = (MODE == MODE_QKV) ? bi[ni] : 0.f;
        #pragma unroll
        for (int mi = 0; mi < 4; mi++) {
          int rh0 = mi * 16 + quad * 4;   // row within half, [0,64)
          if (MODE == MODE_S) {
            #pragma unroll
            for (int r = 0; r < 4; r++)
              smem.epiN[(rh0 + r) * 136 + col] = f2bf(__expf(acc[mi][ni][r] * scale));
          } else if (!vtrans) {
            #pragma unroll
            for (int r = 0; r < 4; r++)
              smem.epiN[(rh0 + r) * 136 + col] = f2bf(acc[mi][ni][r] + bb);
          } else {
            #pragma unroll
            for (int r = 0; r < 4; r += 2) {
              unsigned lo = f2bf(acc[mi][ni][r] + bb);
              unsigned hi = f2bf(acc[mi][ni][r + 1] + bb);
              *(unsigned*)&smem.epiT[col * 72 + rh0 + r] = lo | (hi << 16);
            }
          }
        }
      }
    }
    __syncthreads();

    // coalesced 16B write-out of this half (+ row-sum atomics for MODE_S)
    if (!vtrans) {
      #pragma unroll
      for (int i = 0; i < 4; i++) {
        int flat = i * 2048 + tid * 8;
        int rr = flat >> 7, cc = flat & 127;   // rr in [0,64)
        short8 vline = *(const short8*)&smem.epiN[rr * 136 + cc];
        int grow = bm + half * 64 + rr;
        if (MODE == MODE_S) {
          union { short8 v; unsigned short u[8]; } t; t.v = vline;
          float s8 = 0.f;
          #pragma unroll
          for (int j = 0; j < 8; j++) s8 += bf2f(t.u[j]);
          s8 += __shfl_xor(s8, 1);
          s8 += __shfl_xor(s8, 2);
          s8 += __shfl_xor(s8, 4);
          s8 += __shfl_xor(s8, 8);
          if ((lane & 15) == 0) atomicAdd(&lsum[(long)z * M + grow], s8);
          *(short8*)&O0[(long)z * cZ + (long)grow * N + bn + cc] = vline;
        } else {
          unsigned short* O = (z == 0) ? O0 : O1;
          *(short8*)&O[(long)grow * N + bn + cc] = vline;
        }
      }
    } else {
      #pragma unroll
      for (int i = 0; i < 4; i++) {
        int flat = i * 2048 + tid * 8;
        int rr = flat >> 6, cc = flat & 63;    // rr = d-col [0,128), cc = s [0,64)
        short8 vline = *(const short8*)&smem.epiT[rr * 72 + cc];
        int bb = bm >> 11, s0 = bm & 2047;     // tiles don't straddle batch
        *(short8*)&O2[(long)bb * (1024L * 2048) + (long)(bn + rr) * 2048
                      + s0 + half * 64 + cc] = vline;
      }
    }
    __syncthreads();   // protect epi reuse by next half
  }
}

// Fused prep: [0,4096) x fp32->bf16; [4096,7168) W transpose->bf16;
// [7168,7200) zero the 8192-float lsum buffer.
__global__ __launch_bounds__(256)
void prep_kernel(const float* __restrict__ x, unsigned short* __restrict__ xb,
                 const float* __restrict__ W0, const float* __restrict__ W1,
                 const float* __restrict__ W2, unsigned short* __restrict__ Wt,
                 float* __restrict__ lsum) {
  int blk = blockIdx.x;
  if (blk < 4096) {
    long i = ((long)blk * 256 + threadIdx.x) * 8;
    float4 a = *(const float4*)(x + i);
    float4 b = *(const float4*)(x + i + 4);
    union { int4 v; unsigned short u[8]; } t;
    t.u[0] = f2bf(a.x); t.u[1] = f2bf(a.y); t.u[2] = f2bf(a.z); t.u[3] = f2bf(a.w);
    t.u[4] = f2bf(b.x); t.u[5] = f2bf(b.y); t.u[6] = f2bf(b.z); t.u[7] = f2bf(b.w);
    *(int4*)(xb + i) = t.v;
  } else if (blk < 7168) {
    __shared__ float tile[32][33];
    int tt = blk - 4096;
    int zz = tt >> 10, rem = tt & 1023;
    int kb = (rem >> 5) * 32, nb = (rem & 31) * 32;
    const float* W = (zz == 0) ? W0 : ((zz == 1) ? W1 : W2);
    unsigned short* O = Wt + (long)zz * 1024 * 1024;
    int t = threadIdx.x, tr = t >> 5, tc = t & 31;
    #pragma unroll
    for (int i = 0; i < 4; i++)
      tile[tr + i * 8][tc] = W[(long)(kb + tr + i * 8) * 1024 + nb + tc];
    __syncthreads();
    #pragma unroll
    for (int i = 0; i < 4; i++)
      O[(long)(nb + tr + i * 8) * 1024 + kb + tc] = f2bf(tile[tc][tr + i * 8]);
  } else {
    int i = (blk - 7168) * 256 + threadIdx.x;  // 32*256 = 8192 floats
    lsum[i] = 0.f;
  }
}

extern "C" void kernel_launch(void* const* d_in, const int* in_sizes, int n_in,
                              void* d_out, int out_size, void* d_ws, size_t ws_size,
                              hipStream_t stream) {
  const float* x  = (const float*)d_in[0];
  const float* Wq = (const float*)d_in[1];
  const float* bq = (const float*)d_in[2];
  const float* Wk = (const float*)d_in[3];
  const float* bk = (const float*)d_in[4];
  const float* Wv = (const float*)d_in[5];
  const float* bv = (const float*)d_in[6];
  float* out = (float*)d_out;

  const int B = 4, S = 2048, D = 1024;
  const int M = B * S;
  const float scale = 0.03125f;  // 1/sqrt(1024)

  // xb (16 MiB) + Wt (6 MiB) borrow d_out's first 22 MiB; dead before the
  // PV GEMM overwrites all of d_out.
  unsigned short* xb = (unsigned short*)d_out;
  unsigned short* Wt = xb + (size_t)M * D;
  unsigned short* q  = (unsigned short*)d_ws;
  unsigned short* k  = q + (size_t)M * D;
  unsigned short* vT = k + (size_t)M * D;
  unsigned short* P  = vT + (size_t)M * D;

  size_t need_full = ((size_t)3 * M * D + (size_t)B * S * S) * sizeof(unsigned short)
                   + (size_t)M * sizeof(float);
  const bool full = (ws_size >= need_full);
  float* lsum = full ? (float*)(P + (size_t)B * S * S)
                     : (float*)(P + (size_t)S * S);

  prep_kernel<<<7200, 256, 0, stream>>>(x, xb, Wq, Wk, Wv, Wt, lsum);

  gemm_nt<MODE_QKV><<<dim3(D / 128, M / 128, 3), 256, 0, stream>>>(
      xb, Wt, bq, bk, bv, q, k, vT, nullptr, nullptr,
      M, D, D, 0, (long)D * D, 0, 1.0f);

  if (full) {
    gemm_nt<MODE_S><<<dim3(S / 128, S / 128, B), 256, 0, stream>>>(
        q, k, nullptr, nullptr, nullptr, P, nullptr, nullptr, nullptr, lsum,
        S, S, D, (long)S * D, (long)S * D, (long)S * S, scale);
    gemm_nt<MODE_PV><<<dim3(D / 128, S / 128, B), 256, 0, stream>>>(
        P, vT, nullptr, nullptr, nullptr, nullptr, nullptr, nullptr, out, lsum,
        S, D, S, (long)S * S, (long)D * S, (long)S * D, 1.0f);
  } else {
    for (int b = 0; b < B; b++) {
      const unsigned short* qb = q + (size_t)b * S * D;
      const unsigned short* kb = k + (size_t)b * S * D;
      const unsigned short* vb = vT + (size_t)b * S * D;
      float* ob = out + (size_t)b * S * D;
      gemm_nt<MODE_S><<<dim3(S / 128, S / 128, 1), 256, 0, stream>>>(
          qb, kb, nullptr, nullptr, nullptr, P, nullptr, nullptr, nullptr,
          lsum + (size_t)b * S,
          S, S, D, 0, 0, 0, scale);
      gemm_nt<MODE_PV><<<dim3(D / 128, S / 128, 1), 256, 0, stream>>>(
          P, vb, nullptr, nullptr, nullptr, nullptr, nullptr, nullptr, ob,
          lsum + (size_t)b * S,
          S, D, S, 0, 0, 0, 1.0f);
    }
  }
}

// Round 7
// 238.967 us; speedup vs baseline: 1.1856x; 1.1856x over previous
//
#include <hip/hip_runtime.h>

#define MODE_QKV 0
#define MODE_S   1
#define MODE_PV  2

typedef __attribute__((ext_vector_type(8))) short short8;
typedef __attribute__((ext_vector_type(4))) float floatx4;

typedef const unsigned __attribute__((address_space(1)))* gp_t;
typedef unsigned __attribute__((address_space(3)))* lp_t;

__device__ __forceinline__ void async16(const void* g, void* l) {
  // stages 16B/lane: LDS dest = wave-uniform base + lane*16
  __builtin_amdgcn_global_load_lds((gp_t)g, (lp_t)l, 16, 0, 0);
}

__device__ __forceinline__ unsigned short f2bf(float f) {
  union { float f; unsigned u; } x; x.f = f;
  unsigned r = x.u + 0x7fffu + ((x.u >> 16) & 1u);
  return (unsigned short)(r >> 16);
}
__device__ __forceinline__ float bf2f(unsigned short h) {
  union { unsigned u; float f; } x; x.u = ((unsigned)h) << 16;
  return x.f;
}

// LDS budget pinned to 32768 B (2x16KiB granules -> 4 blocks/CU at bounds(256,4)):
//  - staging: two BK=32 panels (proven conflict-free layout), 32 KB
//  - epilogue HALF-tiles alias the staging space:
//      epiN[64][136]  (normal, 17408 B)   epiT[128][72] (vtrans, 18432 B)
union SmemU {
  struct { unsigned short A[2][4096]; unsigned short B[2][4096]; } st;  // 32768
  unsigned short epiN[64 * 136];
  unsigned short epiT[128 * 72];
};

// ---------------------------------------------------------------------------
// Unified NT bf16 GEMM: A [M][K] k-contig, B [N][K] k-contig, 128x128 tile,
// BK=64 (2 panels), 256 thr = 4 waves, 4x4 of mfma_f32_16x16x32_bf16 / wave.
//   MODE_QKV: z picks B slice + bias + out; z==2 writes v TRANSPOSED [B][D][S]
//   MODE_S:   out bf16 = exp(acc*scale) (scores bounded, no max-subtract
//             needed), row exp-sums atomicAdd'ed into lsum (pre-zeroed)
//   MODE_PV:  out fp32 = acc / lsum[row]
// Grid swizzled in-kernel: XCD-aware 4x4 block squares. Requires
// gridDim.x%4==0, gridDim.y%4==0, total blocks %128==0.
// launch_bounds(256,4): reg cap 128 >= ~124 live (60 VGPR + 64 acc) -- R6's
// (256,5) capped at ~102 and SPILLED acc to scratch (WRITE_SIZE doubled).
// LDS 32768 = 2 granules -> true 4 blocks/CU (R5's 34816 rounded to 3).
// ---------------------------------------------------------------------------
template<int MODE>
__global__ __launch_bounds__(256, 4)
void gemm_nt(const unsigned short* __restrict__ A,
             const unsigned short* __restrict__ Bmat,
             const float* __restrict__ b0, const float* __restrict__ b1,
             const float* __restrict__ b2,
             unsigned short* __restrict__ O0, unsigned short* __restrict__ O1,
             unsigned short* __restrict__ O2,
             float* __restrict__ Of, float* __restrict__ lsum,
             int M, int N, int K, long aZ, long bZ, long cZ, float scale)
{
  __shared__ SmemU smem;

  const int tid = threadIdx.x;
  const int wave = tid >> 6, lane = tid & 63;
  const int wm = wave >> 1, wn = wave & 1;
  const int quad = lane >> 4, l16 = lane & 15;

  // ---- XCD-aware 4x4-square swizzle ----
  const int gx = gridDim.x, gy = gridDim.y;
  int z, bm, bn;
  {
    int f = (blockIdx.z * gy + blockIdx.y) * gx + blockIdx.x;
    int T = gx * gy * (int)gridDim.z;
    int nsq = T >> 7;                 // 4x4-squares per XCD
    int xcd = f & 7, i = f >> 3;
    int sq = xcd * nsq + (i >> 4);
    int w = i & 15;
    int spz = (gx >> 2) * (gy >> 2);  // squares per z-slice
    z = sq / spz;
    int sqr = sq - z * spz;
    int sqm = sqr / (gx >> 2), sqn = sqr - sqm * (gx >> 2);
    bm = (sqm * 4 + (w >> 2)) * 128;
    bn = (sqn * 4 + (w & 3)) * 128;
  }

  const unsigned short* Ap = (MODE == MODE_QKV) ? A : (A + (long)z * aZ);
  const unsigned short* Bp = Bmat + (long)z * bZ;

  floatx4 acc[4][4];
  #pragma unroll
  for (int i = 0; i < 4; i++)
    #pragma unroll
    for (int j = 0; j < 4; j++)
      acc[i][j] = (floatx4){0.f, 0.f, 0.f, 0.f};

  char* asb = (char*)&smem.st.A[0][0] + wave * 1024;
  char* bsb = (char*)&smem.st.B[0][0] + wave * 1024;

  for (int k0 = 0; k0 < K; k0 += 64) {
    #pragma unroll
    for (int p = 0; p < 2; p++) {
      #pragma unroll
      for (int h = 0; h < 2; h++) {
        int flat = tid + h * 256;        // 16B-chunk index within panel
        int r = flat >> 2, c = (flat & 3) << 3;
        async16(Ap + (long)(bm + r) * K + k0 + p * 32 + c,
                asb + p * 8192 + h * 4096);
        async16(Bp + (long)(bn + r) * K + k0 + p * 32 + c,
                bsb + p * 8192 + h * 4096);
      }
    }
    __syncthreads();

    #pragma unroll
    for (int ks = 0; ks < 2; ks++) {
      short8 afr[4], bfr[4];
      #pragma unroll
      for (int i = 0; i < 4; i++)
        afr[i] = *(const short8*)&smem.st.A[ks][(wm * 64 + i * 16 + l16) * 32 + quad * 8];
      #pragma unroll
      for (int i = 0; i < 4; i++)
        bfr[i] = *(const short8*)&smem.st.B[ks][(wn * 64 + i * 16 + l16) * 32 + quad * 8];
      #pragma unroll
      for (int mi = 0; mi < 4; mi++)
        #pragma unroll
        for (int ni = 0; ni < 4; ni++)
          acc[mi][ni] = __builtin_amdgcn_mfma_f32_16x16x32_bf16(
              afr[mi], bfr[ni], acc[mi][ni], 0, 0, 0);
    }
    __syncthreads();
  }
  // (loop-trailing __syncthreads: staging reads complete; epi may alias st)

  // ---- epilogue; C/D layout: col=lane&15, row=quad*4+reg ----
  if (MODE == MODE_PV) {
    // fp32 direct stores, normalized by the row's exp-sum
    #pragma unroll
    for (int mi = 0; mi < 4; mi++) {
      int row0 = bm + wm * 64 + mi * 16 + quad * 4;
      float inv[4];
      #pragma unroll
      for (int r = 0; r < 4; r++)
        inv[r] = 1.0f / lsum[(long)z * M + row0 + r];
      #pragma unroll
      for (int ni = 0; ni < 4; ni++) {
        int col = bn + wn * 64 + ni * 16 + l16;
        #pragma unroll
        for (int r = 0; r < 4; r++)
          Of[(long)z * cZ + (long)(row0 + r) * N + col] = acc[mi][ni][r] * inv[r];
      }
    }
    return;
  }

  const bool vtrans = (MODE == MODE_QKV) && (z == 2);
  float bi[4];
  if (MODE == MODE_QKV) {
    const float* bias = (z == 0) ? b0 : ((z == 1) ? b1 : b2);
    #pragma unroll
    for (int ni = 0; ni < 4; ni++) bi[ni] = bias[bn + wn * 64 + ni * 16 + l16];
  }

  // Two 64-row halves; the two waves with wm==half own the rows of that half.
  #pragma unroll
  for (int half = 0; half < 2; half++) {
    if (wm == half) {
      #pragma unroll
      for (int ni = 0; ni < 4; ni++) {
        int col = wn * 64 + ni * 16 + l16;
        float bb = (MODE == MODE_QKV) ? bi[ni] : 0.f;
        #pragma unroll
        for (int mi = 0; mi < 4; mi++) {
          int rh0 = mi * 16 + quad * 4;   // row within half, [0,64)
          if (MODE == MODE_S) {
            #pragma unroll
            for (int r = 0; r < 4; r++)
              smem.epiN[(rh0 + r) * 136 + col] = f2bf(__expf(acc[mi][ni][r] * scale));
          } else if (!vtrans) {
            #pragma unroll
            for (int r = 0; r < 4; r++)
              smem.epiN[(rh0 + r) * 136 + col] = f2bf(acc[mi][ni][r] + bb);
          } else {
            #pragma unroll
            for (int r = 0; r < 4; r += 2) {
              unsigned lo = f2bf(acc[mi][ni][r] + bb);
              unsigned hi = f2bf(acc[mi][ni][r + 1] + bb);
              *(unsigned*)&smem.epiT[col * 72 + rh0 + r] = lo | (hi << 16);
            }
          }
        }
      }
    }
    __syncthreads();

    // coalesced 16B write-out of this half (+ row-sum atomics for MODE_S)
    if (!vtrans) {
      #pragma unroll
      for (int i = 0; i < 4; i++) {
        int flat = i * 2048 + tid * 8;
        int rr = flat >> 7, cc = flat & 127;   // rr in [0,64)
        short8 vline = *(const short8*)&smem.epiN[rr * 136 + cc];
        int grow = bm + half * 64 + rr;
        if (MODE == MODE_S) {
          union { short8 v; unsigned short u[8]; } t; t.v = vline;
          float s8 = 0.f;
          #pragma unroll
          for (int j = 0; j < 8; j++) s8 += bf2f(t.u[j]);
          s8 += __shfl_xor(s8, 1);
          s8 += __shfl_xor(s8, 2);
          s8 += __shfl_xor(s8, 4);
          s8 += __shfl_xor(s8, 8);
          if ((lane & 15) == 0) atomicAdd(&lsum[(long)z * M + grow], s8);
          *(short8*)&O0[(long)z * cZ + (long)grow * N + bn + cc] = vline;
        } else {
          unsigned short* O = (z == 0) ? O0 : O1;
          *(short8*)&O[(long)grow * N + bn + cc] = vline;
        }
      }
    } else {
      #pragma unroll
      for (int i = 0; i < 4; i++) {
        int flat = i * 2048 + tid * 8;
        int rr = flat >> 6, cc = flat & 63;    // rr = d-col [0,128), cc = s [0,64)
        short8 vline = *(const short8*)&smem.epiT[rr * 72 + cc];
        int bb = bm >> 11, s0 = bm & 2047;     // tiles don't straddle batch
        *(short8*)&O2[(long)bb * (1024L * 2048) + (long)(bn + rr) * 2048
                      + s0 + half * 64 + cc] = vline;
      }
    }
    __syncthreads();   // protect epi reuse by next half
  }
}

// Fused prep: [0,4096) x fp32->bf16; [4096,7168) W transpose->bf16;
// [7168,7200) zero the 8192-float lsum buffer.
__global__ __launch_bounds__(256)
void prep_kernel(const float* __restrict__ x, unsigned short* __restrict__ xb,
                 const float* __restrict__ W0, const float* __restrict__ W1,
                 const float* __restrict__ W2, unsigned short* __restrict__ Wt,
                 float* __restrict__ lsum) {
  int blk = blockIdx.x;
  if (blk < 4096) {
    long i = ((long)blk * 256 + threadIdx.x) * 8;
    float4 a = *(const float4*)(x + i);
    float4 b = *(const float4*)(x + i + 4);
    union { int4 v; unsigned short u[8]; } t;
    t.u[0] = f2bf(a.x); t.u[1] = f2bf(a.y); t.u[2] = f2bf(a.z); t.u[3] = f2bf(a.w);
    t.u[4] = f2bf(b.x); t.u[5] = f2bf(b.y); t.u[6] = f2bf(b.z); t.u[7] = f2bf(b.w);
    *(int4*)(xb + i) = t.v;
  } else if (blk < 7168) {
    __shared__ float tile[32][33];
    int tt = blk - 4096;
    int zz = tt >> 10, rem = tt & 1023;
    int kb = (rem >> 5) * 32, nb = (rem & 31) * 32;
    const float* W = (zz == 0) ? W0 : ((zz == 1) ? W1 : W2);
    unsigned short* O = Wt + (long)zz * 1024 * 1024;
    int t = threadIdx.x, tr = t >> 5, tc = t & 31;
    #pragma unroll
    for (int i = 0; i < 4; i++)
      tile[tr + i * 8][tc] = W[(long)(kb + tr + i * 8) * 1024 + nb + tc];
    __syncthreads();
    #pragma unroll
    for (int i = 0; i < 4; i++)
      O[(long)(nb + tr + i * 8) * 1024 + kb + tc] = f2bf(tile[tc][tr + i * 8]);
  } else {
    int i = (blk - 7168) * 256 + threadIdx.x;  // 32*256 = 8192 floats
    lsum[i] = 0.f;
  }
}

extern "C" void kernel_launch(void* const* d_in, const int* in_sizes, int n_in,
                              void* d_out, int out_size, void* d_ws, size_t ws_size,
                              hipStream_t stream) {
  const float* x  = (const float*)d_in[0];
  const float* Wq = (const float*)d_in[1];
  const float* bq = (const float*)d_in[2];
  const float* Wk = (const float*)d_in[3];
  const float* bk = (const float*)d_in[4];
  const float* Wv = (const float*)d_in[5];
  const float* bv = (const float*)d_in[6];
  float* out = (float*)d_out;

  const int B = 4, S = 2048, D = 1024;
  const int M = B * S;
  const float scale = 0.03125f;  // 1/sqrt(1024)

  // xb (16 MiB) + Wt (6 MiB) borrow d_out's first 22 MiB; dead before the
  // PV GEMM overwrites all of d_out.
  unsigned short* xb = (unsigned short*)d_out;
  unsigned short* Wt = xb + (size_t)M * D;
  unsigned short* q  = (unsigned short*)d_ws;
  unsigned short* k  = q + (size_t)M * D;
  unsigned short* vT = k + (size_t)M * D;
  unsigned short* P  = vT + (size_t)M * D;

  size_t need_full = ((size_t)3 * M * D + (size_t)B * S * S) * sizeof(unsigned short)
                   + (size_t)M * sizeof(float);
  const bool full = (ws_size >= need_full);
  float* lsum = full ? (float*)(P + (size_t)B * S * S)
                     : (float*)(P + (size_t)S * S);

  prep_kernel<<<7200, 256, 0, stream>>>(x, xb, Wq, Wk, Wv, Wt, lsum);

  gemm_nt<MODE_QKV><<<dim3(D / 128, M / 128, 3), 256, 0, stream>>>(
      xb, Wt, bq, bk, bv, q, k, vT, nullptr, nullptr,
      M, D, D, 0, (long)D * D, 0, 1.0f);

  if (full) {
    gemm_nt<MODE_S><<<dim3(S / 128, S / 128, B), 256, 0, stream>>>(
        q, k, nullptr, nullptr, nullptr, P, nullptr, nullptr, nullptr, lsum,
        S, S, D, (long)S * D, (long)S * D, (long)S * S, scale);
    gemm_nt<MODE_PV><<<dim3(D / 128, S / 128, B), 256, 0, stream>>>(
        P, vT, nullptr, nullptr, nullptr, nullptr, nullptr, nullptr, out, lsum,
        S, D, S, (long)S * S, (long)D * S, (long)S * D, 1.0f);
  } else {
    for (int b = 0; b < B; b++) {
      const unsigned short* qb = q + (size_t)b * S * D;
      const unsigned short* kb = k + (size_t)b * S * D;
      const unsigned short* vb = vT + (size_t)b * S * D;
      float* ob = out + (size_t)b * S * D;
      gemm_nt<MODE_S><<<dim3(S / 128, S / 128, 1), 256, 0, stream>>>(
          qb, kb, nullptr, nullptr, nullptr, P, nullptr, nullptr, nullptr,
          lsum + (size_t)b * S,
          S, S, D, 0, 0, 0, scale);
      gemm_nt<MODE_PV><<<dim3(D / 128, S / 128, 1), 256, 0, stream>>>(
          P, vb, nullptr, nullptr, nullptr, nullptr, nullptr, nullptr, ob,
          lsum + (size_t)b * S,
          S, D, S, 0, 0, 0, 1.0f);
    }
  }
}

// Round 8
// 237.169 us; speedup vs baseline: 1.1946x; 1.0076x over previous
//
#include <hip/hip_runtime.h>

#define MODE_QKV 0
#define MODE_S   1
#define MODE_PV  2

typedef __attribute__((ext_vector_type(8))) short short8;
typedef __attribute__((ext_vector_type(4))) float floatx4;

typedef const unsigned __attribute__((address_space(1)))* gp_t;
typedef unsigned __attribute__((address_space(3)))* lp_t;

__device__ __forceinline__ void async16(const void* g, void* l) {
  // stages 16B/lane: LDS dest = wave-uniform base + lane*16
  __builtin_amdgcn_global_load_lds((gp_t)g, (lp_t)l, 16, 0, 0);
}

__device__ __forceinline__ unsigned short f2bf(float f) {
  union { float f; unsigned u; } x; x.f = f;
  unsigned r = x.u + 0x7fffu + ((x.u >> 16) & 1u);
  return (unsigned short)(r >> 16);
}
__device__ __forceinline__ float bf2f(unsigned short h) {
  union { unsigned u; float f; } x; x.u = ((unsigned)h) << 16;
  return x.f;
}

// Templated smem: A staging panels scale with MI (m-tile = MI*32 rows).
//  MI=4: A 2x8KB + B 2x8KB = 32768 B;  MI=8: A 2x16KB + B 2x8KB = 49152 B.
// Epilogue 64-row tiles alias staging after the K-loop.
template<int MI> union SmemT {
  struct { unsigned short A[2][MI * 1024]; unsigned short B[2][4096]; } st;
  unsigned short epiN[64 * 136];
  unsigned short epiT[128 * 72];   // vtrans (QKV z==2, MI=4 only)
};

// ---------------------------------------------------------------------------
// Unified NT bf16 GEMM: A [M][K] k-contig, B [N][K] k-contig.
// Tile = (MI*32) x 128, BK=64 (2 panels), 256 thr = 4 waves (2m x 2n),
// each wave MIx4 of mfma_f32_16x16x32_bf16.
//   MODE_QKV (MI=4): z picks B slice + bias + out; z==2 writes vT [B][D][S]
//   MODE_S   (MI=8): out bf16 = exp(acc*scale); row exp-sums atomicAdd->lsum
//   MODE_PV  (MI=4): out fp32 = acc / lsum[row]
// Grid swizzled in-kernel: XCD-aware 4x4 tile squares. Requires
// gridDim.x%4==0, gridDim.y%4==0, total blocks %128==0.
// Occupancy note (R5-R7): 3 blocks/CU is the HW cap for the MI=4 config
// regardless of LDS 32768 vs 34816 or bounds(4 vs 5); bounds(256,5) SPILLS
// (R6). MI=8 targets m105's measured 823 TF: 2 blocks/CU, 2x tile.
// ---------------------------------------------------------------------------
template<int MODE, int MI>
__global__ __launch_bounds__(256, (MI == 4 ? 4 : 2))
void gemm_nt(const unsigned short* __restrict__ A,
             const unsigned short* __restrict__ Bmat,
             const float* __restrict__ b0, const float* __restrict__ b1,
             const float* __restrict__ b2,
             unsigned short* __restrict__ O0, unsigned short* __restrict__ O1,
             unsigned short* __restrict__ O2,
             float* __restrict__ Of, float* __restrict__ lsum,
             int M, int N, int K, long aZ, long bZ, long cZ, float scale)
{
  __shared__ SmemT<MI> smem;
  const int TM = MI * 32;                 // m-tile rows
  const int APB = MI * 2048;              // A panel bytes

  const int tid = threadIdx.x;
  const int wave = tid >> 6, lane = tid & 63;
  const int wm = wave >> 1, wn = wave & 1;
  const int quad = lane >> 4, l16 = lane & 15;

  // ---- XCD-aware 4x4-square swizzle (tile-index space) ----
  const int gx = gridDim.x, gy = gridDim.y;
  int z, bm, bn;
  {
    int f = (blockIdx.z * gy + blockIdx.y) * gx + blockIdx.x;
    int T = gx * gy * (int)gridDim.z;
    int nsq = T >> 7;                 // 4x4-squares per XCD
    int xcd = f & 7, i = f >> 3;
    int sq = xcd * nsq + (i >> 4);
    int w = i & 15;
    int spz = (gx >> 2) * (gy >> 2);  // squares per z-slice
    z = sq / spz;
    int sqr = sq - z * spz;
    int sqm = sqr / (gx >> 2), sqn = sqr - sqm * (gx >> 2);
    bm = (sqm * 4 + (w >> 2)) * TM;
    bn = (sqn * 4 + (w & 3)) * 128;
  }

  const unsigned short* Ap = (MODE == MODE_QKV) ? A : (A + (long)z * aZ);
  const unsigned short* Bp = Bmat + (long)z * bZ;

  floatx4 acc[MI][4];
  #pragma unroll
  for (int i = 0; i < MI; i++)
    #pragma unroll
    for (int j = 0; j < 4; j++)
      acc[i][j] = (floatx4){0.f, 0.f, 0.f, 0.f};

  char* asb = (char*)&smem.st.A[0][0] + wave * 1024;
  char* bsb = (char*)&smem.st.B[0][0] + wave * 1024;

  for (int k0 = 0; k0 < K; k0 += 64) {
    #pragma unroll
    for (int p = 0; p < 2; p++) {
      #pragma unroll
      for (int h = 0; h < MI / 2; h++) {   // A: MI/2 chunks of 16B per thread
        int flat = tid + h * 256;
        int r = flat >> 2, c = (flat & 3) << 3;
        async16(Ap + (long)(bm + r) * K + k0 + p * 32 + c,
                asb + p * APB + h * 4096);
      }
      #pragma unroll
      for (int h = 0; h < 2; h++) {        // B: 2 chunks per thread
        int flat = tid + h * 256;
        int r = flat >> 2, c = (flat & 3) << 3;
        async16(Bp + (long)(bn + r) * K + k0 + p * 32 + c,
                bsb + p * 8192 + h * 4096);
      }
    }
    __syncthreads();

    #pragma unroll
    for (int ks = 0; ks < 2; ks++) {
      short8 afr[MI], bfr[4];
      #pragma unroll
      for (int i = 0; i < MI; i++)
        afr[i] = *(const short8*)&smem.st.A[ks][(wm * (TM / 2) + i * 16 + l16) * 32 + quad * 8];
      #pragma unroll
      for (int i = 0; i < 4; i++)
        bfr[i] = *(const short8*)&smem.st.B[ks][(wn * 64 + i * 16 + l16) * 32 + quad * 8];
      #pragma unroll
      for (int mi = 0; mi < MI; mi++)
        #pragma unroll
        for (int ni = 0; ni < 4; ni++)
          acc[mi][ni] = __builtin_amdgcn_mfma_f32_16x16x32_bf16(
              afr[mi], bfr[ni], acc[mi][ni], 0, 0, 0);
    }
    __syncthreads();
  }
  // (loop-trailing __syncthreads: staging reads complete; epi may alias st)

  // ---- epilogue; C/D layout: col=lane&15, row=quad*4+reg ----
  if (MODE == MODE_PV) {
    #pragma unroll
    for (int mi = 0; mi < MI; mi++) {
      int row0 = bm + wm * (TM / 2) + mi * 16 + quad * 4;
      float inv[4];
      #pragma unroll
      for (int r = 0; r < 4; r++)
        inv[r] = 1.0f / lsum[(long)z * M + row0 + r];
      #pragma unroll
      for (int ni = 0; ni < 4; ni++) {
        int col = bn + wn * 64 + ni * 16 + l16;
        #pragma unroll
        for (int r = 0; r < 4; r++)
          Of[(long)z * cZ + (long)(row0 + r) * N + col] = acc[mi][ni][r] * inv[r];
      }
    }
    return;
  }

  const bool vtrans = (MODE == MODE_QKV) && (z == 2);
  float bi[4];
  if (MODE == MODE_QKV) {
    const float* bias = (z == 0) ? b0 : ((z == 1) ? b1 : b2);
    #pragma unroll
    for (int ni = 0; ni < 4; ni++) bi[ni] = bias[bn + wn * 64 + ni * 16 + l16];
  }

  // 64-row sections; section qt is owned by wave-row-group qt/(MI/4),
  // mi range starts at (qt%(MI/4))*4.
  #pragma unroll
  for (int qt = 0; qt < MI / 2; qt++) {
    if (wm == qt / (MI / 4)) {
      int mib = (qt % (MI / 4)) * 4;
      #pragma unroll
      for (int ni = 0; ni < 4; ni++) {
        int col = wn * 64 + ni * 16 + l16;
        float bb = (MODE == MODE_QKV) ? bi[ni] : 0.f;
        #pragma unroll
        for (int mo = 0; mo < 4; mo++) {
          int mi = mib + mo;
          int rh0 = mo * 16 + quad * 4;   // row within section, [0,64)
          if (MODE == MODE_S) {
            #pragma unroll
            for (int r = 0; r < 4; r++)
              smem.epiN[(rh0 + r) * 136 + col] = f2bf(__expf(acc[mi][ni][r] * scale));
          } else if (!vtrans) {
            #pragma unroll
            for (int r = 0; r < 4; r++)
              smem.epiN[(rh0 + r) * 136 + col] = f2bf(acc[mi][ni][r] + bb);
          } else {
            #pragma unroll
            for (int r = 0; r < 4; r += 2) {
              unsigned lo = f2bf(acc[mi][ni][r] + bb);
              unsigned hi = f2bf(acc[mi][ni][r + 1] + bb);
              *(unsigned*)&smem.epiT[col * 72 + rh0 + r] = lo | (hi << 16);
            }
          }
        }
      }
    }
    __syncthreads();

    // coalesced 16B write-out of this 64-row section
    if (!vtrans) {
      #pragma unroll
      for (int i = 0; i < 4; i++) {
        int flat = i * 2048 + tid * 8;
        int rr = flat >> 7, cc = flat & 127;   // rr in [0,64)
        short8 vline = *(const short8*)&smem.epiN[rr * 136 + cc];
        int grow = bm + qt * 64 + rr;
        if (MODE == MODE_S) {
          union { short8 v; unsigned short u[8]; } t; t.v = vline;
          float s8 = 0.f;
          #pragma unroll
          for (int j = 0; j < 8; j++) s8 += bf2f(t.u[j]);
          s8 += __shfl_xor(s8, 1);
          s8 += __shfl_xor(s8, 2);
          s8 += __shfl_xor(s8, 4);
          s8 += __shfl_xor(s8, 8);
          if ((lane & 15) == 0) atomicAdd(&lsum[(long)z * M + grow], s8);
          *(short8*)&O0[(long)z * cZ + (long)grow * N + bn + cc] = vline;
        } else {
          unsigned short* O = (z == 0) ? O0 : O1;
          *(short8*)&O[(long)grow * N + bn + cc] = vline;
        }
      }
    } else {
      #pragma unroll
      for (int i = 0; i < 4; i++) {
        int flat = i * 2048 + tid * 8;
        int rr = flat >> 6, cc = flat & 63;    // rr = d-col [0,128), cc = s [0,64)
        short8 vline = *(const short8*)&smem.epiT[rr * 72 + cc];
        int bb = bm >> 11, s0 = bm & 2047;     // tiles don't straddle batch
        *(short8*)&O2[(long)bb * (1024L * 2048) + (long)(bn + rr) * 2048
                      + s0 + qt * 64 + cc] = vline;
      }
    }
    __syncthreads();   // protect epi reuse by next section
  }
}

// Fused prep: [0,4096) x fp32->bf16; [4096,7168) W transpose->bf16;
// [7168,7200) zero the 8192-float lsum buffer.
__global__ __launch_bounds__(256)
void prep_kernel(const float* __restrict__ x, unsigned short* __restrict__ xb,
                 const float* __restrict__ W0, const float* __restrict__ W1,
                 const float* __restrict__ W2, unsigned short* __restrict__ Wt,
                 float* __restrict__ lsum) {
  int blk = blockIdx.x;
  if (blk < 4096) {
    long i = ((long)blk * 256 + threadIdx.x) * 8;
    float4 a = *(const float4*)(x + i);
    float4 b = *(const float4*)(x + i + 4);
    union { int4 v; unsigned short u[8]; } t;
    t.u[0] = f2bf(a.x); t.u[1] = f2bf(a.y); t.u[2] = f2bf(a.z); t.u[3] = f2bf(a.w);
    t.u[4] = f2bf(b.x); t.u[5] = f2bf(b.y); t.u[6] = f2bf(b.z); t.u[7] = f2bf(b.w);
    *(int4*)(xb + i) = t.v;
  } else if (blk < 7168) {
    __shared__ float tile[32][33];
    int tt = blk - 4096;
    int zz = tt >> 10, rem = tt & 1023;
    int kb = (rem >> 5) * 32, nb = (rem & 31) * 32;
    const float* W = (zz == 0) ? W0 : ((zz == 1) ? W1 : W2);
    unsigned short* O = Wt + (long)zz * 1024 * 1024;
    int t = threadIdx.x, tr = t >> 5, tc = t & 31;
    #pragma unroll
    for (int i = 0; i < 4; i++)
      tile[tr + i * 8][tc] = W[(long)(kb + tr + i * 8) * 1024 + nb + tc];
    __syncthreads();
    #pragma unroll
    for (int i = 0; i < 4; i++)
      O[(long)(nb + tr + i * 8) * 1024 + kb + tc] = f2bf(tile[tc][tr + i * 8]);
  } else {
    int i = (blk - 7168) * 256 + threadIdx.x;  // 32*256 = 8192 floats
    lsum[i] = 0.f;
  }
}

extern "C" void kernel_launch(void* const* d_in, const int* in_sizes, int n_in,
                              void* d_out, int out_size, void* d_ws, size_t ws_size,
                              hipStream_t stream) {
  const float* x  = (const float*)d_in[0];
  const float* Wq = (const float*)d_in[1];
  const float* bq = (const float*)d_in[2];
  const float* Wk = (const float*)d_in[3];
  const float* bk = (const float*)d_in[4];
  const float* Wv = (const float*)d_in[5];
  const float* bv = (const float*)d_in[6];
  float* out = (float*)d_out;

  const int B = 4, S = 2048, D = 1024;
  const int M = B * S;
  const float scale = 0.03125f;  // 1/sqrt(1024)

  // xb (16 MiB) + Wt (6 MiB) borrow d_out's first 22 MiB; dead before the
  // PV GEMM overwrites all of d_out.
  unsigned short* xb = (unsigned short*)d_out;
  unsigned short* Wt = xb + (size_t)M * D;
  unsigned short* q  = (unsigned short*)d_ws;
  unsigned short* k  = q + (size_t)M * D;
  unsigned short* vT = k + (size_t)M * D;
  unsigned short* P  = vT + (size_t)M * D;

  size_t need_full = ((size_t)3 * M * D + (size_t)B * S * S) * sizeof(unsigned short)
                   + (size_t)M * sizeof(float);
  const bool full = (ws_size >= need_full);
  float* lsum = full ? (float*)(P + (size_t)B * S * S)
                     : (float*)(P + (size_t)S * S);

  prep_kernel<<<7200, 256, 0, stream>>>(x, xb, Wq, Wk, Wv, Wt, lsum);

  gemm_nt<MODE_QKV, 4><<<dim3(D / 128, M / 128, 3), 256, 0, stream>>>(
      xb, Wt, bq, bk, bv, q, k, vT, nullptr, nullptr,
      M, D, D, 0, (long)D * D, 0, 1.0f);

  if (full) {
    // S: 256x128 tiles -> 512 blocks = one uniform residency round (m105: 823 TF)
    gemm_nt<MODE_S, 8><<<dim3(S / 128, S / 256, B), 256, 0, stream>>>(
        q, k, nullptr, nullptr, nullptr, P, nullptr, nullptr, nullptr, lsum,
        S, S, D, (long)S * D, (long)S * D, (long)S * S, scale);
    gemm_nt<MODE_PV, 4><<<dim3(D / 128, S / 128, B), 256, 0, stream>>>(
        P, vT, nullptr, nullptr, nullptr, nullptr, nullptr, nullptr, out, lsum,
        S, D, S, (long)S * S, (long)D * S, (long)S * D, 1.0f);
  } else {
    for (int b = 0; b < B; b++) {
      const unsigned short* qb = q + (size_t)b * S * D;
      const unsigned short* kb = k + (size_t)b * S * D;
      const unsigned short* vb = vT + (size_t)b * S * D;
      float* ob = out + (size_t)b * S * D;
      gemm_nt<MODE_S, 8><<<dim3(S / 128, S / 256, 1), 256, 0, stream>>>(
          qb, kb, nullptr, nullptr, nullptr, P, nullptr, nullptr, nullptr,
          lsum + (size_t)b * S,
          S, S, D, 0, 0, 0, scale);
      gemm_nt<MODE_PV, 4><<<dim3(D / 128, S / 128, 1), 256, 0, stream>>>(
          P, vb, nullptr, nullptr, nullptr, nullptr, nullptr, nullptr, ob,
          lsum + (size_t)b * S,
          S, D, S, 0, 0, 0, 1.0f);
    }
  }
}